// Round 5
// baseline (184.416 us; speedup 1.0000x reference)
//
#include <hip/hip_runtime.h>

#define HW 4096
#define CCH 128
#define NB 4

typedef short bf16x8 __attribute__((ext_vector_type(8)));
typedef float f32x4 __attribute__((ext_vector_type(4)));

__device__ __forceinline__ unsigned short f2bf(float f){
  union { float fv; unsigned u; } v; v.fv = f;
  unsigned r = v.u + 0x7fffu + ((v.u >> 16) & 1u);
  return (unsigned short)(r >> 16);
}
__device__ __forceinline__ float bf2f(unsigned short u){
  return __uint_as_float(((unsigned)u) << 16);
}
__device__ __forceinline__ f32x4 mfma16(bf16x8 a, bf16x8 b, f32x4 c){
  return __builtin_amdgcn_mfma_f32_16x16x32_bf16(a, b, c, 0, 0, 0);
}
// async global->LDS, 16B/lane; LDS dest = wave-uniform base + lane*16
__device__ __forceinline__ void gll16(const void* g, void* l){
  __builtin_amdgcn_global_load_lds(
      (const __attribute__((address_space(1))) unsigned*)g,
      (__attribute__((address_space(3))) unsigned*)l, 16, 0, 0);
}

// ---------- Kernel A: group-norm stats + weight fp32->bf16 prep ----------
__global__ __launch_bounds__(256) void gn_stats_k(const float* __restrict__ x,
    float* __restrict__ stats,
    const float* __restrict__ wq, const float* __restrict__ wk,
    const float* __restrict__ wv, const float* __restrict__ wp,
    unsigned short* __restrict__ wqb, unsigned short* __restrict__ wkb,
    unsigned short* __restrict__ wvb, unsigned short* __restrict__ wpb){
  int tid = threadIdx.x;
  if (tid < 128){
    int f4 = blockIdx.x * 128 + tid;
    int m = f4 >> 12, e = f4 & 4095;
    const float* s4 = (m == 0) ? wq : ((m == 1) ? wk : ((m == 2) ? wv : wp));
    unsigned short* d4 = (m == 0) ? wqb : ((m == 1) ? wkb : ((m == 2) ? wvb : wpb));
    float4 v = *(const float4*)(s4 + e * 4);
    ushort4 b; b.x = f2bf(v.x); b.y = f2bf(v.y); b.z = f2bf(v.z); b.w = f2bf(v.w);
    *(ushort4*)(d4 + e * 4) = b;
  }
  int gid = blockIdx.x;
  const float4* p = (const float4*)(x + (size_t)gid * 16384);
  float s = 0.f, q = 0.f;
  #pragma unroll
  for (int i = 0; i < 16; i++){
    float4 v = p[tid + 256 * i];
    s += v.x + v.y + v.z + v.w;
    q += v.x * v.x + v.y * v.y + v.z * v.z + v.w * v.w;
  }
  #pragma unroll
  for (int d = 1; d < 64; d <<= 1){ s += __shfl_xor(s, d); q += __shfl_xor(q, d); }
  __shared__ float red[8];
  int w = tid >> 6;
  if ((tid & 63) == 0){ red[2 * w] = s; red[2 * w + 1] = q; }
  __syncthreads();
  if (tid == 0){
    float S = red[0] + red[2] + red[4] + red[6];
    float Q = red[1] + red[3] + red[5] + red[7];
    float mean = S * (1.f / 16384.f);
    float var  = Q * (1.f / 16384.f) - mean * mean;
    stats[2 * gid]     = mean;
    stats[2 * gid + 1] = rsqrtf(var + 1e-5f);
  }
}

// ---------- Kernel B: apply GN + transpose NCHW -> [N, L, C] bf16 ----------
__global__ __launch_bounds__(256) void gn_apply_k(const float* __restrict__ x,
    const float* __restrict__ stats, const float* __restrict__ sc,
    const float* __restrict__ bi, unsigned short* __restrict__ ht){
  int n = blockIdx.y, l0 = blockIdx.x * 32, tid = threadIdx.x;
  __shared__ __align__(16) unsigned short hs[32][136];
  #pragma unroll
  for (int i = 0; i < 16; i++){
    int c = (tid >> 5) + 8 * i;
    int l = tid & 31;
    float v = x[((size_t)(n * CCH + c)) * HW + l0 + l];
    int grp = n * 32 + (c >> 2);
    float r = (v - stats[2 * grp]) * stats[2 * grp + 1] * sc[c] + bi[c];
    hs[l][c] = f2bf(r);
  }
  __syncthreads();
  #pragma unroll
  for (int i = 0; i < 2; i++){
    int ch = tid + 256 * i;
    int l = ch >> 4, cb = (ch & 15) * 8;
    *(uint4*)&ht[((size_t)(n * HW) + l0 + l) * CCH + cb] = *(const uint4*)&hs[l][cb];
  }
}

// ---------- Kernel C: QKV projection, one matmul per block ----------
__global__ __launch_bounds__(256, 3) void qkv_k(const unsigned short* __restrict__ ht,
    const unsigned short* __restrict__ wqb, const unsigned short* __restrict__ wkb,
    const unsigned short* __restrict__ wvb,
    const float* __restrict__ bq, const float* __restrict__ bk,
    const float* __restrict__ bv,
    unsigned short* __restrict__ Qg, unsigned short* __restrict__ Kg,
    unsigned short* __restrict__ Vt){
  int n = blockIdx.y, l0 = blockIdx.x * 64, m = blockIdx.z, tid = threadIdx.x;
  int w = tid >> 6, lane = tid & 63, l15 = lane & 15, g = lane >> 4;
  __shared__ __align__(16) char lds[49152];
  char* hA = lds;            // 16KB [64 rows x 256B], chunk swz c^(row&15)
  char* WB = lds + 16384;    // 32KB [128 rows x 256B], chunk swz c^(row&15)
  const unsigned short* wsrc = (m == 0) ? wqb : ((m == 1) ? wkb : wvb);
  const float* bsrc = (m == 0) ? bq : ((m == 1) ? bk : bv);
  {
    const char* hb = (const char*)ht + ((size_t)(n * HW) + l0) * (CCH * 2);
    #pragma unroll
    for (int i = 0; i < 4; i++){
      int T = (4 * w + i) * 64 + lane;
      int row = T >> 4, c16 = (T & 15) ^ (row & 15);
      gll16(hb + row * 256 + c16 * 16, hA + (4 * w + i) * 1024);
    }
    const char* wb2 = (const char*)wsrc;
    #pragma unroll
    for (int i = 0; i < 8; i++){
      int T = (8 * w + i) * 64 + lane;
      int row = T >> 4, c16 = (T & 15) ^ (row & 15);
      gll16(wb2 + row * 256 + c16 * 16, WB + (8 * w + i) * 1024);
    }
  }
  __syncthreads();
  bf16x8 a[4];
  #pragma unroll
  for (int kc = 0; kc < 4; kc++)
    a[kc] = *(const bf16x8*)(hA + (16 * w + l15) * 256 + ((4 * kc + g) ^ l15) * 16);
  f32x4 acc[8];
  #pragma unroll
  for (int ct = 0; ct < 8; ct++) acc[ct] = (f32x4)(0.f);
  #pragma unroll
  for (int ct = 0; ct < 8; ct++)
    #pragma unroll
    for (int kc = 0; kc < 4; kc++){
      bf16x8 bfr = *(const bf16x8*)(WB + (16 * ct + l15) * 256 + ((4 * kc + g) ^ l15) * 16);
      acc[ct] = mfma16(a[kc], bfr, acc[ct]);
    }
  __syncthreads();   // all waves done reading WB; reuse as output-stage LDS
  if (m < 2){
    float qs = (m == 0) ? 0.08838834764831845f : 1.0f;
    unsigned short* dst = (m == 0) ? Qg : Kg;
    unsigned short* os = (unsigned short*)(lds + 16384);  // [64][136]
    #pragma unroll
    for (int ct = 0; ct < 8; ct++){
      int o = 16 * ct + l15;
      float bias = bsrc[o];
      #pragma unroll
      for (int r = 0; r < 4; r++)
        os[(16 * w + 4 * g + r) * 136 + o] = f2bf((acc[ct][r] + bias) * qs);
    }
    __syncthreads();
    #pragma unroll
    for (int i = 0; i < 4; i++){
      int T = tid + 256 * i;
      int row = T >> 4, cb = T & 15;
      *(uint4*)&dst[((size_t)(n * HW) + l0 + row) * CCH + cb * 8] =
          *(const uint4*)&os[row * 136 + cb * 8];
    }
  } else {
    unsigned short* os = (unsigned short*)(lds + 16384);  // [128][72]
    #pragma unroll
    for (int ct = 0; ct < 8; ct++){
      int o = 16 * ct + l15;
      float bias = bsrc[o];
      #pragma unroll
      for (int r = 0; r < 4; r++)
        os[o * 72 + 16 * w + 4 * g + r] = f2bf(acc[ct][r] + bias);
    }
    __syncthreads();
    #pragma unroll
    for (int i = 0; i < 4; i++){
      int T = tid + 256 * i;
      int row = T >> 3, c = T & 7;
      *(uint4*)&Vt[((size_t)(n * CCH) + row) * HW + l0 + c * 8] =
          *(const uint4*)&os[row * 72 + c * 8];
    }
  }
}

// ---------- Kernel D: flash attention, LDS-dbuf pipeline, 1 barrier/iter ----
// LDS: 2 x (K 16KB + V 16KB) double-buffer + per-wave Ps (4 x 2304B) = 73KB
// -> 2 blocks/CU. gll(t+1) issued before compute(t); the single end-of-iter
// barrier's vmcnt drain lands after the full compute phase (latency hidden).
__global__ __launch_bounds__(256, 2) void attn_k(const unsigned short* __restrict__ Qg,
    const unsigned short* __restrict__ Kg, const unsigned short* __restrict__ Vt,
    unsigned short* __restrict__ Op, float* __restrict__ Ml, int lsp){
  // chunked bijective XCD swizzle; decode (q fastest, sp, n): each XCD's
  // resident blocks share one n -> K/V/Q slice is L2-resident
  int nbk = gridDim.x, cpx = nbk >> 3, b = blockIdx.x;
  int swz = (b & 7) * cpx + (b >> 3);
  int q0 = (swz & 63) * 64;
  int rest = swz >> 6;
  int splits = 1 << lsp;
  int sp = rest & (splits - 1);
  int n = rest >> lsp;
  int kvs = HW >> lsp, nt = 64 >> lsp;
  int tid = threadIdx.x;
  int w = tid >> 6, lane = tid & 63, l15 = lane & 15, g = lane >> 4;
  __shared__ __align__(16) char lds[74752];
  char* Pw = lds + 65536 + w * 2304;   // per-wave P [16][72] shorts — no barrier

  bf16x8 qf[4];
  #pragma unroll
  for (int kc = 0; kc < 4; kc++)
    qf[kc] = *reinterpret_cast<const bf16x8*>(
        &Qg[((size_t)(n * HW) + q0 + 16 * w + l15) * CCH + 32 * kc + 8 * g]);
  f32x4 ov[8];
  #pragma unroll
  for (int i = 0; i < 8; i++) ov[i] = (f32x4)(0.f);
  float mrun[4] = {-3.0e38f, -3.0e38f, -3.0e38f, -3.0e38f};
  float lrun[4] = {0.f, 0.f, 0.f, 0.f};

  const char* kp[4]; const char* vp[4];
  {
    const char* kbase = (const char*)Kg + ((size_t)(n * HW) + sp * kvs) * (CCH * 2);
    const char* vbase = (const char*)Vt + (size_t)(n * CCH) * (HW * 2) + (size_t)sp * kvs * 2;
    #pragma unroll
    for (int i = 0; i < 4; i++){
      int C = (w * 4 + i) * 64 + lane;
      int row = C >> 4, c16 = (C & 15) ^ (row & 15);
      kp[i] = kbase + row * 256 + c16 * 16;
      int vrow = C >> 3, c8 = (C & 7) ^ (vrow & 7);
      vp[i] = vbase + (size_t)vrow * (HW * 2) + c8 * 16;
    }
  }

  // prologue: stage tile 0 into buffer 0
  #pragma unroll
  for (int i = 0; i < 4; i++) gll16(kp[i], lds + w * 4096 + i * 1024);
  #pragma unroll
  for (int i = 0; i < 4; i++) gll16(vp[i], lds + 16384 + w * 4096 + i * 1024);
  __syncthreads();

  for (int t = 0; t < nt; t++){
    char* cur = lds + ((t & 1) ? 32768 : 0);
    if (t + 1 < nt){   // prefetch next tile into the other buffer NOW
      char* nb = lds + ((t & 1) ? 0 : 32768);
      #pragma unroll
      for (int i = 0; i < 4; i++)
        gll16(kp[i] + (size_t)(t + 1) * 16384, nb + w * 4096 + i * 1024);
      #pragma unroll
      for (int i = 0; i < 4; i++)
        gll16(vp[i] + (size_t)(t + 1) * 128, nb + 16384 + w * 4096 + i * 1024);
    }
    char* Ks = cur; char* Vs = cur + 16384;

    f32x4 s[4];
    __builtin_amdgcn_s_setprio(1);
    #pragma unroll
    for (int ct = 0; ct < 4; ct++){
      f32x4 acc = (f32x4)(0.f);
      #pragma unroll
      for (int kc = 0; kc < 4; kc++){
        bf16x8 kf = *(const bf16x8*)(Ks + (16 * ct + l15) * 256 + ((4 * kc + g) ^ l15) * 16);
        acc = mfma16(qf[kc], kf, acc);
      }
      s[ct] = acc;
    }
    __builtin_amdgcn_s_setprio(0);
    // online softmax with defer-rescale (THR=8)
    float mx[4];
    #pragma unroll
    for (int r = 0; r < 4; r++)
      mx[r] = fmaxf(fmaxf(s[0][r], s[1][r]), fmaxf(s[2][r], s[3][r]));
    #pragma unroll
    for (int d = 1; d < 16; d <<= 1)
      #pragma unroll
      for (int r = 0; r < 4; r++) mx[r] = fmaxf(mx[r], __shfl_xor(mx[r], d));
    int need = 0;
    #pragma unroll
    for (int r = 0; r < 4; r++) need |= (mx[r] > mrun[r] + 8.0f) ? 1 : 0;
    if (__any(need)){
      float al[4];
      #pragma unroll
      for (int r = 0; r < 4; r++){
        float mn = fmaxf(mrun[r], mx[r]);
        al[r] = __expf(mrun[r] - mn);
        mrun[r] = mn;
        lrun[r] *= al[r];
      }
      #pragma unroll
      for (int ct = 0; ct < 8; ct++)
        #pragma unroll
        for (int r = 0; r < 4; r++) ov[ct][r] *= al[r];
    }
    #pragma unroll
    for (int ct = 0; ct < 4; ct++)
      #pragma unroll
      for (int r = 0; r < 4; r++) s[ct][r] = __expf(s[ct][r] - mrun[r]);
    float rs[4];
    #pragma unroll
    for (int r = 0; r < 4; r++) rs[r] = s[0][r] + s[1][r] + s[2][r] + s[3][r];
    #pragma unroll
    for (int d = 1; d < 16; d <<= 1)
      #pragma unroll
      for (int r = 0; r < 4; r++) rs[r] += __shfl_xor(rs[r], d);
    #pragma unroll
    for (int r = 0; r < 4; r++) lrun[r] += rs[r];

    // P -> per-wave LDS (write->read ordered by DS pipe within the wave)
    #pragma unroll
    for (int ct = 0; ct < 4; ct++)
      #pragma unroll
      for (int r = 0; r < 4; r++)
        *(unsigned short*)(Pw + (4 * g + r) * 144 + (16 * ct + l15) * 2) = f2bf(s[ct][r]);
    __builtin_amdgcn_s_setprio(1);
    #pragma unroll
    for (int ct = 0; ct < 8; ct++){
      #pragma unroll
      for (int kc = 0; kc < 2; kc++){
        bf16x8 pa = *(const bf16x8*)(Pw + l15 * 144 + (32 * kc + 8 * g) * 2);
        bf16x8 vf = *(const bf16x8*)(Vs + (16 * ct + l15) * 128 + ((4 * kc + g) ^ (l15 & 7)) * 16);
        ov[ct] = mfma16(pa, vf, ov[ct]);
      }
    }
    __builtin_amdgcn_s_setprio(0);
    __syncthreads();   // drains gll(t+1); hands buffers over for next iter
  }
  size_t obase = (size_t)((sp * NB + n) * HW);
  #pragma unroll
  for (int ct = 0; ct < 8; ct++){
    int o = 16 * ct + l15;
    #pragma unroll
    for (int r = 0; r < 4; r++){
      int l = q0 + 16 * w + 4 * g + r;
      Op[(obase + l) * CCH + o] = f2bf(ov[ct][r]);
    }
  }
  if (l15 == 0){
    #pragma unroll
    for (int r = 0; r < 4; r++){
      int l = q0 + 16 * w + 4 * g + r;
      Ml[(obase + l) * 2]     = mrun[r];
      Ml[(obase + l) * 2 + 1] = lrun[r];
    }
  }
}

// ---------- Kernel E: combine splits + output projection + residual ----------
__global__ __launch_bounds__(256) void projout_k(const unsigned short* __restrict__ Op,
    const float* __restrict__ Ml, const unsigned short* __restrict__ wpb,
    const float* __restrict__ bp, const float* __restrict__ x,
    float* __restrict__ out, int splits){
  int n = blockIdx.y, l0 = blockIdx.x * 32, tid = threadIdx.x;
  int w = tid >> 6, lane = tid & 63, l15 = lane & 15, g = lane >> 4;
  __shared__ __align__(16) unsigned short hs[32][136];
  __shared__ __align__(16) char WB[32768];
  {
    const char* wb2 = (const char*)wpb;
    #pragma unroll
    for (int i = 0; i < 8; i++){
      int T = (8 * w + i) * 64 + lane;
      int row = T >> 4, c16 = (T & 15) ^ (row & 15);
      gll16(wb2 + row * 256 + c16 * 16, WB + (8 * w + i) * 1024);
    }
  }
  const size_t SSTR = (size_t)NB * HW;
  #pragma unroll
  for (int i = 0; i < 2; i++){
    int T = tid + 256 * i;
    int row = T >> 4, cb = (T & 15) * 8;
    size_t gl = (size_t)n * HW + l0 + row;
    float mv = -3.0e38f;
    #pragma unroll
    for (int s = 0; s < 4; s++)
      if (s < splits) mv = fmaxf(mv, Ml[(s * SSTR + gl) * 2]);
    float fa[8];
    #pragma unroll
    for (int j = 0; j < 8; j++) fa[j] = 0.f;
    float denom = 0.f;
    #pragma unroll
    for (int s = 0; s < 4; s++){
      if (s < splits){
        float wgt = __expf(Ml[(s * SSTR + gl) * 2] - mv);
        denom += wgt * Ml[(s * SSTR + gl) * 2 + 1];
        uint4 a = *(const uint4*)&Op[(s * SSTR + gl) * CCH + cb];
        const unsigned short* au = (const unsigned short*)&a;
        #pragma unroll
        for (int j = 0; j < 8; j++) fa[j] += wgt * bf2f(au[j]);
      }
    }
    float inv = 1.f / denom;
    #pragma unroll
    for (int j = 0; j < 8; j++) hs[row][cb + j] = f2bf(fa[j] * inv);
  }
  __syncthreads();
  int rt = w & 1, cg = w >> 1;
  bf16x8 a[4];
  #pragma unroll
  for (int kc = 0; kc < 4; kc++)
    a[kc] = *reinterpret_cast<const bf16x8*>(&hs[16 * rt + l15][32 * kc + 8 * g]);
  f32x4 acc[4];
  #pragma unroll
  for (int ci = 0; ci < 4; ci++) acc[ci] = (f32x4)(0.f);
  #pragma unroll
  for (int ci = 0; ci < 4; ci++){
    int o = 16 * (cg * 4 + ci) + l15;
    #pragma unroll
    for (int kc = 0; kc < 4; kc++){
      bf16x8 bfr = *(const bf16x8*)(WB + o * 256 + ((4 * kc + g) ^ l15) * 16);
      acc[ci] = mfma16(a[kc], bfr, acc[ci]);
    }
  }
  #pragma unroll
  for (int ci = 0; ci < 4; ci++){
    int o = 16 * (cg * 4 + ci) + l15;
    float bias = bp[o];
    size_t base = ((size_t)(n * CCH) + o) * HW + l0 + 16 * rt + 4 * g;
    float4 xr = *(const float4*)&x[base];
    float4 res;
    res.x = xr.x + acc[ci][0] + bias;
    res.y = xr.y + acc[ci][1] + bias;
    res.z = xr.z + acc[ci][2] + bias;
    res.w = xr.w + acc[ci][3] + bias;
    *(float4*)&out[base] = res;
  }
}

extern "C" void kernel_launch(void* const* d_in, const int* in_sizes, int n_in,
                              void* d_out, int out_size, void* d_ws, size_t ws_size,
                              hipStream_t stream){
  const float* x    = (const float*)d_in[0];
  const float* gnsc = (const float*)d_in[1];
  const float* gnb  = (const float*)d_in[2];
  const float* wq   = (const float*)d_in[3];
  const float* bq   = (const float*)d_in[4];
  const float* wk   = (const float*)d_in[5];
  const float* bk   = (const float*)d_in[6];
  const float* wv   = (const float*)d_in[7];
  const float* bv   = (const float*)d_in[8];
  const float* wp   = (const float*)d_in[9];
  const float* bp   = (const float*)d_in[10];
  float* out = (float*)d_out;

  char* ws = (char*)d_ws;
  const size_t BUF = (size_t)NB * HW * CCH * sizeof(unsigned short);  // 4 MiB
  const size_t WOFF = 4096;
  const size_t HTOFF = WOFF + 4 * 32768;
  const size_t NEED4 = HTOFF + 8 * BUF + (size_t)4 * NB * HW * 2 * sizeof(float);
  const int lsp = (ws_size >= NEED4) ? 2 : 1;
  const int splits = 1 << lsp;

  float* stats        = (float*)ws;
  unsigned short* wqb = (unsigned short*)(ws + WOFF);
  unsigned short* wkb = (unsigned short*)(ws + WOFF + 32768);
  unsigned short* wvb = (unsigned short*)(ws + WOFF + 65536);
  unsigned short* wpb = (unsigned short*)(ws + WOFF + 98304);
  unsigned short* ht  = (unsigned short*)(ws + HTOFF);
  unsigned short* Qg  = (unsigned short*)(ws + HTOFF + BUF);
  unsigned short* Kg  = (unsigned short*)(ws + HTOFF + 2 * BUF);
  unsigned short* Vt  = (unsigned short*)(ws + HTOFF + 3 * BUF);
  unsigned short* Op  = (unsigned short*)(ws + HTOFF + 4 * BUF);
  float*          Ml  = (float*)(ws + HTOFF + 4 * BUF + (size_t)splits * BUF);

  gn_stats_k<<<128, 256, 0, stream>>>(x, stats, wq, wk, wv, wp, wqb, wkb, wvb, wpb);
  gn_apply_k<<<dim3(128, NB), 256, 0, stream>>>(x, stats, gnsc, gnb, ht);
  qkv_k<<<dim3(64, NB, 3), 256, 0, stream>>>(ht, wqb, wkb, wvb, bq, bk, bv, Qg, Kg, Vt);
  attn_k<<<dim3(64 * NB * splits), 256, 0, stream>>>(Qg, Kg, Vt, Op, Ml, lsp);
  projout_k<<<dim3(128, NB), 256, 0, stream>>>(Op, Ml, wpb, bp, x, out, splits);
}

// Round 6
// 157.635 us; speedup vs baseline: 1.1699x; 1.1699x over previous
//
#include <hip/hip_runtime.h>

#define HW 4096
#define CCH 128
#define NB 4

typedef short bf16x8 __attribute__((ext_vector_type(8)));
typedef float f32x4 __attribute__((ext_vector_type(4)));

__device__ __forceinline__ unsigned short f2bf(float f){
  union { float fv; unsigned u; } v; v.fv = f;
  unsigned r = v.u + 0x7fffu + ((v.u >> 16) & 1u);
  return (unsigned short)(r >> 16);
}
__device__ __forceinline__ float bf2f(unsigned short u){
  return __uint_as_float(((unsigned)u) << 16);
}
__device__ __forceinline__ f32x4 mfma16(bf16x8 a, bf16x8 b, f32x4 c){
  return __builtin_amdgcn_mfma_f32_16x16x32_bf16(a, b, c, 0, 0, 0);
}
// async global->LDS, 16B/lane; LDS dest = wave-uniform base + lane*16
__device__ __forceinline__ void gll16(const void* g, void* l){
  __builtin_amdgcn_global_load_lds(
      (const __attribute__((address_space(1))) unsigned*)g,
      (__attribute__((address_space(3))) unsigned*)l, 16, 0, 0);
}

// ---------- Kernel A: group-norm stats + weight fp32->bf16 prep ----------
__global__ __launch_bounds__(256) void gn_stats_k(const float* __restrict__ x,
    float* __restrict__ stats,
    const float* __restrict__ wq, const float* __restrict__ wk,
    const float* __restrict__ wv, const float* __restrict__ wp,
    unsigned short* __restrict__ wqb, unsigned short* __restrict__ wkb,
    unsigned short* __restrict__ wvb, unsigned short* __restrict__ wpb){
  int tid = threadIdx.x;
  if (tid < 128){
    int f4 = blockIdx.x * 128 + tid;
    int m = f4 >> 12, e = f4 & 4095;
    const float* s4 = (m == 0) ? wq : ((m == 1) ? wk : ((m == 2) ? wv : wp));
    unsigned short* d4 = (m == 0) ? wqb : ((m == 1) ? wkb : ((m == 2) ? wvb : wpb));
    float4 v = *(const float4*)(s4 + e * 4);
    ushort4 b; b.x = f2bf(v.x); b.y = f2bf(v.y); b.z = f2bf(v.z); b.w = f2bf(v.w);
    *(ushort4*)(d4 + e * 4) = b;
  }
  int gid = blockIdx.x;
  const float4* p = (const float4*)(x + (size_t)gid * 16384);
  float s = 0.f, q = 0.f;
  #pragma unroll
  for (int i = 0; i < 16; i++){
    float4 v = p[tid + 256 * i];
    s += v.x + v.y + v.z + v.w;
    q += v.x * v.x + v.y * v.y + v.z * v.z + v.w * v.w;
  }
  #pragma unroll
  for (int d = 1; d < 64; d <<= 1){ s += __shfl_xor(s, d); q += __shfl_xor(q, d); }
  __shared__ float red[8];
  int w = tid >> 6;
  if ((tid & 63) == 0){ red[2 * w] = s; red[2 * w + 1] = q; }
  __syncthreads();
  if (tid == 0){
    float S = red[0] + red[2] + red[4] + red[6];
    float Q = red[1] + red[3] + red[5] + red[7];
    float mean = S * (1.f / 16384.f);
    float var  = Q * (1.f / 16384.f) - mean * mean;
    stats[2 * gid]     = mean;
    stats[2 * gid + 1] = rsqrtf(var + 1e-5f);
  }
}

// ---------- Kernel B: apply GN + transpose NCHW -> [N, L, C] bf16 ----------
__global__ __launch_bounds__(256) void gn_apply_k(const float* __restrict__ x,
    const float* __restrict__ stats, const float* __restrict__ sc,
    const float* __restrict__ bi, unsigned short* __restrict__ ht){
  int n = blockIdx.y, l0 = blockIdx.x * 32, tid = threadIdx.x;
  __shared__ __align__(16) unsigned short hs[32][136];
  #pragma unroll
  for (int i = 0; i < 16; i++){
    int c = (tid >> 5) + 8 * i;
    int l = tid & 31;
    float v = x[((size_t)(n * CCH + c)) * HW + l0 + l];
    int grp = n * 32 + (c >> 2);
    float r = (v - stats[2 * grp]) * stats[2 * grp + 1] * sc[c] + bi[c];
    hs[l][c] = f2bf(r);
  }
  __syncthreads();
  #pragma unroll
  for (int i = 0; i < 2; i++){
    int ch = tid + 256 * i;
    int l = ch >> 4, cb = (ch & 15) * 8;
    *(uint4*)&ht[((size_t)(n * HW) + l0 + l) * CCH + cb] = *(const uint4*)&hs[l][cb];
  }
}

// ---------- Kernel C: QKV projection, one matmul per block ----------
__global__ __launch_bounds__(256, 3) void qkv_k(const unsigned short* __restrict__ ht,
    const unsigned short* __restrict__ wqb, const unsigned short* __restrict__ wkb,
    const unsigned short* __restrict__ wvb,
    const float* __restrict__ bq, const float* __restrict__ bk,
    const float* __restrict__ bv,
    unsigned short* __restrict__ Qg, unsigned short* __restrict__ Kg,
    unsigned short* __restrict__ Vt){
  int n = blockIdx.y, l0 = blockIdx.x * 64, m = blockIdx.z, tid = threadIdx.x;
  int w = tid >> 6, lane = tid & 63, l15 = lane & 15, g = lane >> 4;
  __shared__ __align__(16) char lds[49152];
  char* hA = lds;            // 16KB [64 rows x 256B], chunk swz c^(row&15)
  char* WB = lds + 16384;    // 32KB [128 rows x 256B], chunk swz c^(row&15)
  const unsigned short* wsrc = (m == 0) ? wqb : ((m == 1) ? wkb : wvb);
  const float* bsrc = (m == 0) ? bq : ((m == 1) ? bk : bv);
  {
    const char* hb = (const char*)ht + ((size_t)(n * HW) + l0) * (CCH * 2);
    #pragma unroll
    for (int i = 0; i < 4; i++){
      int T = (4 * w + i) * 64 + lane;
      int row = T >> 4, c16 = (T & 15) ^ (row & 15);
      gll16(hb + row * 256 + c16 * 16, hA + (4 * w + i) * 1024);
    }
    const char* wb2 = (const char*)wsrc;
    #pragma unroll
    for (int i = 0; i < 8; i++){
      int T = (8 * w + i) * 64 + lane;
      int row = T >> 4, c16 = (T & 15) ^ (row & 15);
      gll16(wb2 + row * 256 + c16 * 16, WB + (8 * w + i) * 1024);
    }
  }
  __syncthreads();
  bf16x8 a[4];
  #pragma unroll
  for (int kc = 0; kc < 4; kc++)
    a[kc] = *(const bf16x8*)(hA + (16 * w + l15) * 256 + ((4 * kc + g) ^ l15) * 16);
  f32x4 acc[8];
  #pragma unroll
  for (int ct = 0; ct < 8; ct++) acc[ct] = (f32x4)(0.f);
  #pragma unroll
  for (int ct = 0; ct < 8; ct++)
    #pragma unroll
    for (int kc = 0; kc < 4; kc++){
      bf16x8 bfr = *(const bf16x8*)(WB + (16 * ct + l15) * 256 + ((4 * kc + g) ^ l15) * 16);
      acc[ct] = mfma16(a[kc], bfr, acc[ct]);
    }
  __syncthreads();   // all waves done reading WB; reuse as output-stage LDS
  if (m < 2){
    float qs = (m == 0) ? 0.08838834764831845f : 1.0f;
    unsigned short* dst = (m == 0) ? Qg : Kg;
    unsigned short* os = (unsigned short*)(lds + 16384);  // [64][136]
    #pragma unroll
    for (int ct = 0; ct < 8; ct++){
      int o = 16 * ct + l15;
      float bias = bsrc[o];
      #pragma unroll
      for (int r = 0; r < 4; r++)
        os[(16 * w + 4 * g + r) * 136 + o] = f2bf((acc[ct][r] + bias) * qs);
    }
    __syncthreads();
    #pragma unroll
    for (int i = 0; i < 4; i++){
      int T = tid + 256 * i;
      int row = T >> 4, cb = T & 15;
      *(uint4*)&dst[((size_t)(n * HW) + l0 + row) * CCH + cb * 8] =
          *(const uint4*)&os[row * 136 + cb * 8];
    }
  } else {
    unsigned short* os = (unsigned short*)(lds + 16384);  // [128][72]
    #pragma unroll
    for (int ct = 0; ct < 8; ct++){
      int o = 16 * ct + l15;
      float bias = bsrc[o];
      #pragma unroll
      for (int r = 0; r < 4; r++)
        os[o * 72 + 16 * w + 4 * g + r] = f2bf(acc[ct][r] + bias);
    }
    __syncthreads();
    #pragma unroll
    for (int i = 0; i < 4; i++){
      int T = tid + 256 * i;
      int row = T >> 3, c = T & 7;
      *(uint4*)&Vt[((size_t)(n * CCH) + row) * HW + l0 + c * 8] =
          *(const uint4*)&os[row * 72 + c * 8];
    }
  }
}

// ---------- Kernel D: flash attention, swapped-operand MFMA ----------
// QK^T computed as mfma(K, Q): lane (g,l15) holds S[q=l15][kv=16ct+4g+r]
// -> softmax is in-lane + 2 shfl; P stays in registers (16 bpermute
// redistribution), PV = mfma(V^T, P). No P LDS, 2 barriers/iter, 32KB LDS,
// 4 blocks/CU.
__global__ __launch_bounds__(256, 4) void attn_k(const unsigned short* __restrict__ Qg,
    const unsigned short* __restrict__ Kg, const unsigned short* __restrict__ Vt,
    unsigned short* __restrict__ Op, float* __restrict__ Ml, int lsp){
  // chunked bijective XCD swizzle; decode (q fastest, sp, n)
  int nbk = gridDim.x, cpx = nbk >> 3, b = blockIdx.x;
  int swz = (b & 7) * cpx + (b >> 3);
  int q0 = (swz & 63) * 64;
  int rest = swz >> 6;
  int splits = 1 << lsp;
  int sp = rest & (splits - 1);
  int n = rest >> lsp;
  int kvs = HW >> lsp, nt = 64 >> lsp;
  int tid = threadIdx.x;
  int w = tid >> 6, lane = tid & 63, l15 = lane & 15, g = lane >> 4;
  __shared__ __align__(16) char lds[32768];
  char* Ks = lds;            // 16 KB [64 x 256B], chunk swz c^(row&15)
  char* Vs = lds + 16384;    // 16 KB [128 x 128B], chunk swz c^(row&7)

  bf16x8 qf[4];   // B-operand: lane holds Q[q=l15][c=32kc+8g..]
  #pragma unroll
  for (int kc = 0; kc < 4; kc++)
    qf[kc] = *reinterpret_cast<const bf16x8*>(
        &Qg[((size_t)(n * HW) + q0 + 16 * w + l15) * CCH + 32 * kc + 8 * g]);
  f32x4 ov[8];    // O^T: ov[ct][r] = O[q=l15][c=16ct+4g+r]
  #pragma unroll
  for (int i = 0; i < 8; i++) ov[i] = (f32x4)(0.f);
  float mrun = -3.0e38f, lrun = 0.f;   // per-lane (replicated over 4 g-lanes)

  const char* kp[4]; const char* vp[4];
  {
    const char* kbase = (const char*)Kg + ((size_t)(n * HW) + sp * kvs) * (CCH * 2);
    const char* vbase = (const char*)Vt + (size_t)(n * CCH) * (HW * 2) + (size_t)sp * kvs * 2;
    #pragma unroll
    for (int i = 0; i < 4; i++){
      int C = (w * 4 + i) * 64 + lane;
      int row = C >> 4, c16 = (C & 15) ^ (row & 15);
      kp[i] = kbase + row * 256 + c16 * 16;
      int vrow = C >> 3, c8 = (C & 7) ^ (vrow & 7);
      vp[i] = vbase + (size_t)vrow * (HW * 2) + c8 * 16;
    }
  }
  char* kl = Ks + w * 4096;
  char* vl = Vs + w * 4096;

  for (int t = 0; t < nt; t++){
    __syncthreads();                 // B1: prev iter done with Ks/Vs
    #pragma unroll
    for (int i = 0; i < 4; i++) gll16(kp[i] + (size_t)t * 16384, kl + i * 1024);
    #pragma unroll
    for (int i = 0; i < 4; i++) gll16(vp[i] + (size_t)t * 128,   vl + i * 1024);
    __syncthreads();                 // B2: K/V tile visible

    // S^T = K Q^T: s[ct][r] = S[q=l15][kv=16ct+4g+r]
    f32x4 s[4];
    __builtin_amdgcn_s_setprio(1);
    #pragma unroll
    for (int ct = 0; ct < 4; ct++){
      f32x4 acc = (f32x4)(0.f);
      #pragma unroll
      for (int kc = 0; kc < 4; kc++){
        bf16x8 kf = *(const bf16x8*)(Ks + (16 * ct + l15) * 256 + ((4 * kc + g) ^ l15) * 16);
        acc = mfma16(kf, qf[kc], acc);   // swapped operands
      }
      s[ct] = acc;
    }
    __builtin_amdgcn_s_setprio(0);

    // in-lane softmax (16 scores of one q-row per lane) + 2-shfl reduce
    float mx = -3.0e38f;
    #pragma unroll
    for (int ct = 0; ct < 4; ct++)
      #pragma unroll
      for (int r = 0; r < 4; r++) mx = fmaxf(mx, s[ct][r]);
    mx = fmaxf(mx, __shfl_xor(mx, 16));
    mx = fmaxf(mx, __shfl_xor(mx, 32));
    if (__any(mx > mrun + 8.0f)){    // defer-rescale (THR=8)
      float mn = fmaxf(mrun, mx);
      float al = __expf(mrun - mn);
      mrun = mn; lrun *= al;
      #pragma unroll
      for (int ct = 0; ct < 8; ct++)
        #pragma unroll
        for (int r = 0; r < 4; r++) ov[ct][r] *= al;
    }
    float rs = 0.f;
    #pragma unroll
    for (int ct = 0; ct < 4; ct++)
      #pragma unroll
      for (int r = 0; r < 4; r++){
        float e = __expf(s[ct][r] - mrun);
        s[ct][r] = e;
        rs += e;
      }
    rs += __shfl_xor(rs, 16);
    rs += __shfl_xor(rs, 32);
    lrun += rs;

    // pack P to bf16 pairs: up[ct][h] covers kv pair-index 8ct+2g+h
    unsigned up[4][2];
    #pragma unroll
    for (int ct = 0; ct < 4; ct++)
      #pragma unroll
      for (int h = 0; h < 2; h++)
        up[ct][h] = (unsigned)f2bf(s[ct][2 * h]) |
                    ((unsigned)f2bf(s[ct][2 * h + 1]) << 16);
    // redistribute: pb[kc] slot j = kv pair 16kc+4g+j, from lane
    // g_s=(j+4(g&1))>>1, reg u[2kc+(g>>1)][j&1]
    union { unsigned u[2][4]; bf16x8 v[2]; } pb;
    #pragma unroll
    for (int kc = 0; kc < 2; kc++)
      #pragma unroll
      for (int j = 0; j < 4; j++){
        int src = (((j + ((g & 1) << 2)) >> 1) << 4) + l15;
        unsigned v0 = (unsigned)__shfl((int)up[2 * kc][j & 1], src);
        unsigned v1 = (unsigned)__shfl((int)up[2 * kc + 1][j & 1], src);
        pb.u[kc][j] = (g & 2) ? v1 : v0;
      }

    // O^T += V^T P^T: A = V^T fragment (same vf read), B = P (registers)
    __builtin_amdgcn_s_setprio(1);
    #pragma unroll
    for (int ct = 0; ct < 8; ct++){
      #pragma unroll
      for (int kc = 0; kc < 2; kc++){
        bf16x8 vf = *(const bf16x8*)(Vs + (16 * ct + l15) * 128 + ((4 * kc + g) ^ (l15 & 7)) * 16);
        ov[ct] = mfma16(vf, pb.v[kc], ov[ct]);
      }
    }
    __builtin_amdgcn_s_setprio(0);
  }
  // epilogue: unnormalized O~ + (m, l); lane holds channels 16ct+4g..+3 of q=l15
  float inv = 1.f / lrun;
  (void)inv;
  size_t obase = (size_t)((sp * NB + n) * HW);
  size_t qrow = obase + q0 + 16 * w + l15;
  #pragma unroll
  for (int ct = 0; ct < 8; ct++){
    ushort4 pk;
    pk.x = f2bf(ov[ct][0]); pk.y = f2bf(ov[ct][1]);
    pk.z = f2bf(ov[ct][2]); pk.w = f2bf(ov[ct][3]);
    *(ushort4*)&Op[qrow * CCH + 16 * ct + 4 * g] = pk;
  }
  if (g == 0){
    Ml[qrow * 2]     = mrun;
    Ml[qrow * 2 + 1] = lrun;
  }
}

// ---------- Kernel E: combine splits + output projection + residual ----------
__global__ __launch_bounds__(256) void projout_k(const unsigned short* __restrict__ Op,
    const float* __restrict__ Ml, const unsigned short* __restrict__ wpb,
    const float* __restrict__ bp, const float* __restrict__ x,
    float* __restrict__ out, int splits){
  int n = blockIdx.y, l0 = blockIdx.x * 32, tid = threadIdx.x;
  int w = tid >> 6, lane = tid & 63, l15 = lane & 15, g = lane >> 4;
  __shared__ __align__(16) unsigned short hs[32][136];
  __shared__ __align__(16) char WB[32768];
  {
    const char* wb2 = (const char*)wpb;
    #pragma unroll
    for (int i = 0; i < 8; i++){
      int T = (8 * w + i) * 64 + lane;
      int row = T >> 4, c16 = (T & 15) ^ (row & 15);
      gll16(wb2 + row * 256 + c16 * 16, WB + (8 * w + i) * 1024);
    }
  }
  const size_t SSTR = (size_t)NB * HW;
  #pragma unroll
  for (int i = 0; i < 2; i++){
    int T = tid + 256 * i;
    int row = T >> 4, cb = (T & 15) * 8;
    size_t gl = (size_t)n * HW + l0 + row;
    float mv = -3.0e38f;
    #pragma unroll
    for (int s = 0; s < 4; s++)
      if (s < splits) mv = fmaxf(mv, Ml[(s * SSTR + gl) * 2]);
    float fa[8];
    #pragma unroll
    for (int j = 0; j < 8; j++) fa[j] = 0.f;
    float denom = 0.f;
    #pragma unroll
    for (int s = 0; s < 4; s++){
      if (s < splits){
        float wgt = __expf(Ml[(s * SSTR + gl) * 2] - mv);
        denom += wgt * Ml[(s * SSTR + gl) * 2 + 1];
        uint4 a = *(const uint4*)&Op[(s * SSTR + gl) * CCH + cb];
        const unsigned short* au = (const unsigned short*)&a;
        #pragma unroll
        for (int j = 0; j < 8; j++) fa[j] += wgt * bf2f(au[j]);
      }
    }
    float inv = 1.f / denom;
    #pragma unroll
    for (int j = 0; j < 8; j++) hs[row][cb + j] = f2bf(fa[j] * inv);
  }
  __syncthreads();
  int rt = w & 1, cg = w >> 1;
  bf16x8 a[4];
  #pragma unroll
  for (int kc = 0; kc < 4; kc++)
    a[kc] = *reinterpret_cast<const bf16x8*>(&hs[16 * rt + l15][32 * kc + 8 * g]);
  f32x4 acc[4];
  #pragma unroll
  for (int ci = 0; ci < 4; ci++) acc[ci] = (f32x4)(0.f);
  #pragma unroll
  for (int ci = 0; ci < 4; ci++){
    int o = 16 * (cg * 4 + ci) + l15;
    #pragma unroll
    for (int kc = 0; kc < 4; kc++){
      bf16x8 bfr = *(const bf16x8*)(WB + o * 256 + ((4 * kc + g) ^ l15) * 16);
      acc[ci] = mfma16(a[kc], bfr, acc[ci]);
    }
  }
  #pragma unroll
  for (int ci = 0; ci < 4; ci++){
    int o = 16 * (cg * 4 + ci) + l15;
    float bias = bp[o];
    size_t base = ((size_t)(n * CCH) + o) * HW + l0 + 16 * rt + 4 * g;
    float4 xr = *(const float4*)&x[base];
    float4 res;
    res.x = xr.x + acc[ci][0] + bias;
    res.y = xr.y + acc[ci][1] + bias;
    res.z = xr.z + acc[ci][2] + bias;
    res.w = xr.w + acc[ci][3] + bias;
    *(float4*)&out[base] = res;
  }
}

extern "C" void kernel_launch(void* const* d_in, const int* in_sizes, int n_in,
                              void* d_out, int out_size, void* d_ws, size_t ws_size,
                              hipStream_t stream){
  const float* x    = (const float*)d_in[0];
  const float* gnsc = (const float*)d_in[1];
  const float* gnb  = (const float*)d_in[2];
  const float* wq   = (const float*)d_in[3];
  const float* bq   = (const float*)d_in[4];
  const float* wk   = (const float*)d_in[5];
  const float* bk   = (const float*)d_in[6];
  const float* wv   = (const float*)d_in[7];
  const float* bv   = (const float*)d_in[8];
  const float* wp   = (const float*)d_in[9];
  const float* bp   = (const float*)d_in[10];
  float* out = (float*)d_out;

  char* ws = (char*)d_ws;
  const size_t BUF = (size_t)NB * HW * CCH * sizeof(unsigned short);  // 4 MiB
  const size_t WOFF = 4096;
  const size_t HTOFF = WOFF + 4 * 32768;
  const size_t NEED4 = HTOFF + 8 * BUF + (size_t)4 * NB * HW * 2 * sizeof(float);
  const int lsp = (ws_size >= NEED4) ? 2 : 1;
  const int splits = 1 << lsp;

  float* stats        = (float*)ws;
  unsigned short* wqb = (unsigned short*)(ws + WOFF);
  unsigned short* wkb = (unsigned short*)(ws + WOFF + 32768);
  unsigned short* wvb = (unsigned short*)(ws + WOFF + 65536);
  unsigned short* wpb = (unsigned short*)(ws + WOFF + 98304);
  unsigned short* ht  = (unsigned short*)(ws + HTOFF);
  unsigned short* Qg  = (unsigned short*)(ws + HTOFF + BUF);
  unsigned short* Kg  = (unsigned short*)(ws + HTOFF + 2 * BUF);
  unsigned short* Vt  = (unsigned short*)(ws + HTOFF + 3 * BUF);
  unsigned short* Op  = (unsigned short*)(ws + HTOFF + 4 * BUF);
  float*          Ml  = (float*)(ws + HTOFF + 4 * BUF + (size_t)splits * BUF);

  gn_stats_k<<<128, 256, 0, stream>>>(x, stats, wq, wk, wv, wp, wqb, wkb, wvb, wpb);
  gn_apply_k<<<dim3(128, NB), 256, 0, stream>>>(x, stats, gnsc, gnb, ht);
  qkv_k<<<dim3(64, NB, 3), 256, 0, stream>>>(ht, wqb, wkb, wvb, bq, bk, bv, Qg, Kg, Vt);
  attn_k<<<dim3(64 * NB * splits), 256, 0, stream>>>(Qg, Kg, Vt, Op, Ml, lsp);
  projout_k<<<dim3(128, NB), 256, 0, stream>>>(Op, Ml, wpb, bp, x, out, splits);
}